// Round 13
// baseline (299.192 us; speedup 1.0000x reference)
//
#include <hip/hip_runtime.h>
#include <math.h>

#define POOL 7
#define NCELL 49
#define NCH 256
#define CH_SPLIT 32           // 32000 blocks; 8 ch/block, 2 ch/wave
#define CHPB (NCH / CH_SPLIT)
#define CHPW (CHPB / 4)       // 2 channels per wave, both prefetched up front
#define LDSF 640              // floats per channel window slot
#define NIT_S 10              // scalar fallback staging iters: 10*64 = 640
#define NBUCK 512             // sort buckets: level(2b)|batch(1b)|qy(3b)|qx(3b)
#define TABDW 24              // dwords per (box,lane) tab entry (96B)

typedef __attribute__((address_space(1))) void global_void;
typedef __attribute__((address_space(3))) void lds_void;
__device__ __forceinline__ void stage4(const float* g, float* l) {
    __builtin_amdgcn_global_load_lds((global_void*)g, (lds_void*)l, 4, 0, 0);
}
__device__ __forceinline__ void stage16(const float* g, float* l) {
    __builtin_amdgcn_global_load_lds((global_void*)g, (lds_void*)l, 16, 0, 0);
}
__device__ __forceinline__ void vwait0() {
    asm volatile("s_waitcnt vmcnt(0)" ::: "memory");
}

// ---- per-box parameters (computed once; loaded as 64B). ngrp<0 => scalar path.
struct BoxP {
    int W, bidx, y0, x0a, wwa, ngrp, x0, ww, packed;
    float x1, y1, bin_w, bin_h;
};

__device__ __forceinline__ BoxP compute_boxp(const float* boxes, const int* bidxp, int n)
{
    BoxP P;
    float bx1 = boxes[4 * n + 0], by1 = boxes[4 * n + 1];
    float bx2 = boxes[4 * n + 2], by2 = boxes[4 * n + 3];
    float area = (by2 - by1) * (bx2 - bx1);
    float lvlf = logf(sqrtf(area)) * 1.4426950408889634f; // log2(sqrt(area))
    int level = (int)fminf(fmaxf(rintf(lvlf) + 4.0f, 0.0f), 3.0f);
    int W = 256 >> level;
    float scale = (float)W;
    P.W = W;
    P.bidx = bidxp[n];
    P.x1 = bx1 * scale;
    P.y1 = by1 * scale;
    P.bin_w = fmaxf((bx2 - bx1) * scale, 1.0f) * (1.0f / POOL);
    P.bin_h = fmaxf((by2 - by1) * scale, 1.0f) * (1.0f / POOL);

    float yA = P.y1 + P.bin_h * 0.25f, yB = P.y1 + P.bin_h * 6.75f;
    float xA = P.x1 + P.bin_w * 0.25f, xB = P.x1 + P.bin_w * 6.75f;
    int y0  = (int)floorf(fminf(fmaxf(yA, 0.f), (float)(W - 1)));
    int y1h = min((int)floorf(fminf(fmaxf(yB, 0.f), (float)(W - 1))) + 1, W - 1);
    int x0  = (int)floorf(fminf(fmaxf(xA, 0.f), (float)(W - 1)));
    x0 = min(x0, W - 2);                       // pair base can be one left of first xlo
    int x1p = min((int)floorf(fminf(fmaxf(xB, 0.f), (float)(W - 1))) + 1, W - 1);
    int ww = x1p - x0 + 1;
    int wh = y1h - y0 + 1;

    int x0a = x0 & ~3;
    int wwa = ((x1p - x0a + 1) + 3) & ~3;
    if ((wwa & 7) == 0 && (wwa + 4) * wh <= LDSF) wwa += 4;  // bank-stride rule
    int padded = wwa * wh;

    P.y0 = y0; P.x0 = x0; P.x0a = x0a; P.wwa = wwa; P.ww = ww;
    P.ngrp = (padded <= LDSF) ? (wwa >> 2) * wh : -1;
    int whc = min(wh, LDSF / ww);
    P.packed = ww * whc;
    return P;
}

// ---- per-lane sample table: BYTE offsets + premultiplied weights ----
struct TabR {
    int o0[4], o1[4];
    float w00[4], w01[4], w10[4], w11[4];
};

__device__ __forceinline__ void make_tab_arrays(
    int lane, int W, int rs, int xb, int y0,
    float x1, float y1, float bin_w, float bin_h, TabR& tb)
{
    int cell = (lane < NCELL) ? lane : (NCELL - 1);
    int py = cell / POOL, px = cell % POOL;
#pragma unroll
    for (int s = 0; s < 4; ++s) {
        int sy = s >> 1, sx = s & 1;
        float y = y1 + bin_h * ((float)py + ((float)sy + 0.5f) * 0.5f);
        float x = x1 + bin_w * ((float)px + ((float)sx + 0.5f) * 0.5f);
        bool v = (y > -1.f) && (y < (float)W) && (x > -1.f) && (x < (float)W);
        float yc = fminf(fmaxf(y, 0.f), (float)(W - 1));
        float xc = fminf(fmaxf(x, 0.f), (float)(W - 1));
        int ylo = (int)floorf(yc), xlo = (int)floorf(xc);
        int yhi = min(ylo + 1, W - 1);
        float fy = yc - (float)ylo, fx = xc - (float)xlo;
        float vv = v ? 0.25f : 0.f;            // validity + 1/(SR*SR)
        int bxp = min(xlo, W - 2);             // keep float-pair in-row
        bool in = (xlo == bxp);
        float wx0 = in ? (1.f - fx) : 0.f;
        float wx1 = in ? fx : 1.f;
        float wr0 = (1.f - fy) * vv, wr1 = fy * vv;
        tb.o0[s] = ((ylo - y0) * rs + (bxp - xb)) * 4;   // byte offsets
        tb.o1[s] = ((yhi - y0) * rs + (bxp - xb)) * 4;
        tb.w00[s] = wr0 * wx0; tb.w01[s] = wr0 * wx1;
        tb.w10[s] = wr1 * wx0; tb.w11[s] = wr1 * wx1;
    }
}

// Plain-C consume: compiler merges pair reads to ds_read2_b32 and emits
// fine-grained lgkmcnt, interleaving FMAs with LDS returns (no asm fences).
__device__ __forceinline__ float consume(const float* cb, const TabR& tb)
{
    const char* b = (const char*)cb;
    float acc = 0.f;
#pragma unroll
    for (int s = 0; s < 4; ++s) {
        const float* q0 = (const float*)(b + tb.o0[s]);
        const float* q1 = (const float*)(b + tb.o1[s]);
        acc += tb.w00[s] * q0[0] + tb.w01[s] * q0[1]
             + tb.w10[s] * q1[0] + tb.w11[s] * q1[1];
    }
    return acc;
}

// ---- x4 path: 2-channel all-prefetch, one vmcnt rendezvous per task ----
// L0,L1 issued back-to-back return ~together, so a single vmcnt(0) exposes
// no more latency than the split ledger did, and makes the (plain-C) tab
// load queue position irrelevant. Stores regular cached (WRITE at floor).
template <int NIT4>
__device__ __forceinline__ void box_x4(
    const float* fbase, float* outp, float* sm, int lane,
    int W, int HW, int wwa, int y0, int x0a, int ngrp, const TabR& tb)
{
    int g_off[NIT4];
    bool act[NIT4];
    int wwa4 = wwa >> 2;
#pragma unroll
    for (int k = 0; k < NIT4; ++k) {
        int idx = k * 64 + lane;
        act[k] = idx < ngrp;
        int ii = act[k] ? idx : 0;
        int r = ii / wwa4;
        int c = ii - r * wwa4;
        g_off[k] = (y0 + r) * W + x0a + c * 4;   // 16B-aligned (W%4==0, x0a%4==0)
    }
#pragma unroll
    for (int k = 0; k < NIT4; ++k)
        if (act[k]) stage16(fbase + g_off[k], sm + k * 256);
#pragma unroll
    for (int k = 0; k < NIT4; ++k)
        if (act[k]) stage16(fbase + (size_t)HW + g_off[k], sm + LDSF + k * 256);

    vwait0();
    float r0 = consume(sm, tb);
    if (lane < NCELL) outp[0] = r0;
    float r1 = consume(sm + LDSF, tb);
    if (lane < NCELL) outp[(size_t)NCELL] = r1;
}

// ---- scalar fallback for rare oversized padded windows ----
__device__ __forceinline__ void box_s(
    const float* fbase, float* outp, float* sm, int lane,
    int W, int HW, int ww, int y0, int x0, int packed, const TabR& tb)
{
    int g_off[NIT_S];
#pragma unroll
    for (int k = 0; k < NIT_S; ++k) {
        int idx = k * 64 + lane;
        idx = (idx < packed) ? idx : 0;
        int r = idx / ww;
        int c = idx - r * ww;
        g_off[k] = (y0 + r) * W + (x0 + c);
    }
#pragma unroll
    for (int k = 0; k < NIT_S; ++k) stage4(fbase + g_off[k], sm + k * 64);
#pragma unroll
    for (int k = 0; k < NIT_S; ++k) stage4(fbase + (size_t)HW + g_off[k], sm + LDSF + k * 64);

    vwait0();
    float r0 = consume(sm, tb);
    if (lane < NCELL) outp[0] = r0;
    float r1 = consume(sm + LDSF, tb);
    if (lane < NCELL) outp[(size_t)NCELL] = r1;
}

// ---- box ordering + per-box param precompute (sort kernel) ----
__device__ __forceinline__ int box_key(const float* boxes, const int* bidx, int n)
{
    float bx1 = boxes[4 * n + 0], by1 = boxes[4 * n + 1];
    float bx2 = boxes[4 * n + 2], by2 = boxes[4 * n + 3];
    float area = (by2 - by1) * (bx2 - bx1);
    float lvlf = logf(sqrtf(area)) * 1.4426950408889634f;
    int level = (int)fminf(fmaxf(rintf(lvlf) + 4.0f, 0.0f), 3.0f);
    int b = bidx[n] & 1;
    float cx = 0.5f * (bx1 + bx2), cy = 0.5f * (by1 + by2);
    int qx = min(7, max(0, (int)(cx * 8.0f)));
    int qy = min(7, max(0, (int)(cy * 8.0f)));
    return (((((level << 1) | b) << 3) | qy) << 3) | qx;   // < NBUCK
}

__global__ __launch_bounds__(NBUCK) void box_sort_kernel(
    const float* __restrict__ boxes, const int* __restrict__ bidx,
    int* __restrict__ perm, int* __restrict__ prm, int N)
{
    __shared__ int h0[NBUCK], h1[NBUCK];
    const int t = threadIdx.x;
    h0[t] = 0;
    __syncthreads();
    for (int n = t; n < N; n += NBUCK)
        atomicAdd(&h0[box_key(boxes, bidx, n)], 1);
    __syncthreads();
    int* src = h0; int* dst = h1;
    for (int off = 1; off < NBUCK; off <<= 1) {
        dst[t] = src[t] + ((t >= off) ? src[t - off] : 0);
        __syncthreads();
        int* tmp = src; src = dst; dst = tmp;
    }
    dst[t] = (t == 0) ? 0 : src[t - 1];   // exclusive base
    __syncthreads();
    for (int n = t; n < N; n += NBUCK) {
        int slot = atomicAdd(&dst[box_key(boxes, bidx, n)], 1);
        perm[slot] = n;
    }
    if (prm) {
        for (int n = t; n < N; n += NBUCK) {
            BoxP P = compute_boxp(boxes, bidx, n);
            int4* o = (int4*)(prm + (size_t)n * 16);
            o[0] = make_int4(P.W, P.bidx, P.y0, P.x0a);
            o[1] = make_int4(P.wwa, P.ngrp, P.x0, P.ww);
            o[2] = make_int4(P.packed, __float_as_int(P.x1),
                             __float_as_int(P.y1), __float_as_int(P.bin_w));
            o[3] = make_int4(__float_as_int(P.bin_h), 0, 0, 0);
        }
    }
}

// ---- tab kernel: per-(box,lane) sample table, computed ONCE per box ----
// Replaces ~90 VALU/wave-task of make_tab recomputation (identical in all
// 128 waves of a box) with 6 coalesced dwordx4 loads in the main kernel.
__global__ __launch_bounds__(256) void box_tab_kernel(
    const float* __restrict__ boxes, const int* __restrict__ bidx,
    int* __restrict__ tab, int N)
{
    int wid = blockIdx.x * 4 + (threadIdx.x >> 6);
    int lane = threadIdx.x & 63;
    if (wid >= N) return;
    BoxP P = compute_boxp(boxes, bidx, wid);
    int rs = (P.ngrp >= 0) ? P.wwa : P.ww;
    int xb = (P.ngrp >= 0) ? P.x0a : P.x0;
    TabR tb;
    make_tab_arrays(lane, P.W, rs, xb, P.y0, P.x1, P.y1, P.bin_w, P.bin_h, tb);
    int4* d = (int4*)(tab + ((size_t)wid * 64 + lane) * TABDW);
    d[0] = make_int4(tb.o0[0], tb.o0[1], tb.o0[2], tb.o0[3]);
    d[1] = make_int4(tb.o1[0], tb.o1[1], tb.o1[2], tb.o1[3]);
    d[2] = make_int4(__float_as_int(tb.w00[0]), __float_as_int(tb.w01[0]),
                     __float_as_int(tb.w00[1]), __float_as_int(tb.w01[1]));
    d[3] = make_int4(__float_as_int(tb.w00[2]), __float_as_int(tb.w01[2]),
                     __float_as_int(tb.w00[3]), __float_as_int(tb.w01[3]));
    d[4] = make_int4(__float_as_int(tb.w10[0]), __float_as_int(tb.w11[0]),
                     __float_as_int(tb.w10[1]), __float_as_int(tb.w11[1]));
    d[5] = make_int4(__float_as_int(tb.w10[2]), __float_as_int(tb.w11[2]),
                     __float_as_int(tb.w10[3]), __float_as_int(tb.w11[3]));
}

// grid(32, N): linear id = c + 32*n -> XCD = c%8; channel slices pinned to L2.
__global__ __launch_bounds__(256, 8) void roi_align_fpn_kernel(
    const float* __restrict__ p2, const float* __restrict__ p3,
    const float* __restrict__ p4, const float* __restrict__ p5,
    const float* __restrict__ boxes, const int* __restrict__ bidx,
    const int* __restrict__ perm, const int* __restrict__ prm,
    const int* __restrict__ tab,
    float* __restrict__ out, int N)
{
    __shared__ float smem[4][CHPW][LDSF];   // 20480 B -> 8 blocks/CU (= caps)
    const int n = perm ? perm[blockIdx.y] : (int)blockIdx.y;
    const int t = threadIdx.x;
    const int wave = t >> 6;
    const int lane = t & 63;

    BoxP P;
    if (prm) {
        const int4* ip = (const int4*)(prm + (size_t)n * 16);
        int4 q0 = ip[0], q1 = ip[1], q2 = ip[2], q3 = ip[3];
        P.W = q0.x;  P.bidx = q0.y;  P.y0 = q0.z;  P.x0a = q0.w;
        P.wwa = q1.x; P.ngrp = q1.y; P.x0 = q1.z;  P.ww = q1.w;
        P.packed = q2.x;
        P.x1 = __int_as_float(q2.y); P.y1 = __int_as_float(q2.z);
        P.bin_w = __int_as_float(q2.w); P.bin_h = __int_as_float(q3.x);
    } else {
        P = compute_boxp(boxes, bidx, n);
    }

    TabR tb;
    if (tab) {
        const int4* tp = (const int4*)(tab + ((size_t)n * 64 + lane) * TABDW);
        int4 a = tp[0], b = tp[1], c = tp[2], d = tp[3], e = tp[4], f = tp[5];
        tb.o0[0] = a.x; tb.o0[1] = a.y; tb.o0[2] = a.z; tb.o0[3] = a.w;
        tb.o1[0] = b.x; tb.o1[1] = b.y; tb.o1[2] = b.z; tb.o1[3] = b.w;
        tb.w00[0] = __int_as_float(c.x); tb.w01[0] = __int_as_float(c.y);
        tb.w00[1] = __int_as_float(c.z); tb.w01[1] = __int_as_float(c.w);
        tb.w00[2] = __int_as_float(d.x); tb.w01[2] = __int_as_float(d.y);
        tb.w00[3] = __int_as_float(d.z); tb.w01[3] = __int_as_float(d.w);
        tb.w10[0] = __int_as_float(e.x); tb.w11[0] = __int_as_float(e.y);
        tb.w10[1] = __int_as_float(e.z); tb.w11[1] = __int_as_float(e.w);
        tb.w10[2] = __int_as_float(f.x); tb.w11[2] = __int_as_float(f.y);
        tb.w10[3] = __int_as_float(f.z); tb.w11[3] = __int_as_float(f.w);
    } else {
        int rs = (P.ngrp >= 0) ? P.wwa : P.ww;
        int xb = (P.ngrp >= 0) ? P.x0a : P.x0;
        make_tab_arrays(lane, P.W, rs, xb, P.y0, P.x1, P.y1, P.bin_w, P.bin_h, tb);
    }

    const int W = P.W;
    const int HW = W * W;
    const float* feat = (W == 256) ? p2 : (W == 128) ? p3 : (W == 64) ? p4 : p5;
    feat += (size_t)P.bidx * NCH * HW;

    const int ch0 = blockIdx.x * CHPB + wave * CHPW;
    const float* fbase = feat + (size_t)ch0 * HW;
    float* sm = &smem[wave][0][0];
    int cell = (lane < NCELL) ? lane : (NCELL - 1);
    float* outp = out + (size_t)n * NCH * NCELL + (size_t)ch0 * NCELL + cell;

    if (P.ngrp >= 0) {
        int nit4 = (P.ngrp + 63) >> 6;         // in {1,2,3}
        if (nit4 == 1)      box_x4<1>(fbase, outp, sm, lane, W, HW, P.wwa, P.y0, P.x0a, P.ngrp, tb);
        else if (nit4 == 2) box_x4<2>(fbase, outp, sm, lane, W, HW, P.wwa, P.y0, P.x0a, P.ngrp, tb);
        else                box_x4<3>(fbase, outp, sm, lane, W, HW, P.wwa, P.y0, P.x0a, P.ngrp, tb);
    } else {
        box_s(fbase, outp, sm, lane, W, HW, P.ww, P.y0, P.x0, P.packed, tb);
    }
}

extern "C" void kernel_launch(void* const* d_in, const int* in_sizes, int n_in,
                              void* d_out, int out_size, void* d_ws, size_t ws_size,
                              hipStream_t stream) {
    const float* p2    = (const float*)d_in[0];
    const float* p3    = (const float*)d_in[1];
    const float* p4    = (const float*)d_in[2];
    const float* p5    = (const float*)d_in[3];
    const float* boxes = (const float*)d_in[4];
    const int*   bidx  = (const int*)d_in[5];
    float* out = (float*)d_out;
    int N = in_sizes[5];
    int* perm = nullptr;
    int* prm  = nullptr;
    int* tab  = nullptr;
    size_t permB = ((size_t)N * 4 + 15) & ~(size_t)15;   // 16B-align
    size_t prmB  = (size_t)N * 64;
    size_t tabB  = (size_t)N * 64 * TABDW * 4;           // ~6.1 MB @ N=1000
    if (d_ws && ws_size >= permB + prmB + tabB) {
        perm = (int*)d_ws;
        prm  = (int*)((char*)d_ws + permB);
        tab  = (int*)((char*)d_ws + permB + prmB);
        box_sort_kernel<<<1, NBUCK, 0, stream>>>(boxes, bidx, perm, prm, N);
        box_tab_kernel<<<(N + 3) / 4, 256, 0, stream>>>(boxes, bidx, tab, N);
    } else if (d_ws && ws_size >= permB + prmB) {
        perm = (int*)d_ws;
        prm  = (int*)((char*)d_ws + permB);
        box_sort_kernel<<<1, NBUCK, 0, stream>>>(boxes, bidx, perm, prm, N);
    } else if (d_ws && ws_size >= (size_t)N * 4) {
        perm = (int*)d_ws;
        box_sort_kernel<<<1, NBUCK, 0, stream>>>(boxes, bidx, perm, nullptr, N);
    }
    dim3 grid(CH_SPLIT, N);
    roi_align_fpn_kernel<<<grid, 256, 0, stream>>>(p2, p3, p4, p5, boxes, bidx, perm, prm, tab, out, N);
}

// Round 14
// 268.340 us; speedup vs baseline: 1.1150x; 1.1150x over previous
//
#include <hip/hip_runtime.h>
#include <math.h>

#define POOL 7
#define NCELL 49
#define NCH 256
#define CH_SPLIT 32           // 32000 blocks; 8 ch/block, 2 ch/wave
#define CHPB (NCH / CH_SPLIT)
#define CHPW (CHPB / 4)       // 2 channels per wave, both prefetched up front
#define LDSF 640              // floats per channel window slot
#define NIT_S 10              // scalar fallback staging iters: 10*64 = 640
#define NBUCK 512             // sort buckets: level(2b)|batch(1b)|qy(3b)|qx(3b)

typedef __attribute__((address_space(1))) void global_void;
typedef __attribute__((address_space(3))) void lds_void;
__device__ __forceinline__ void stage4(const float* g, float* l) {
    __builtin_amdgcn_global_load_lds((global_void*)g, (lds_void*)l, 4, 0, 0);
}
__device__ __forceinline__ void stage16(const float* g, float* l) {
    __builtin_amdgcn_global_load_lds((global_void*)g, (lds_void*)l, 16, 0, 0);
}
__device__ __forceinline__ void vwait0() {
    asm volatile("s_waitcnt vmcnt(0)" ::: "memory");
}

// ---- per-box parameters (computed once in sort kernel; loaded as 64B).
// ngrp<0 => scalar fallback path.
struct BoxP {
    int W, bidx, y0, x0a, wwa, ngrp, x0, ww, packed;
    float x1, y1, bin_w, bin_h;
};

__device__ __forceinline__ BoxP compute_boxp(const float* boxes, const int* bidxp, int n)
{
    BoxP P;
    float bx1 = boxes[4 * n + 0], by1 = boxes[4 * n + 1];
    float bx2 = boxes[4 * n + 2], by2 = boxes[4 * n + 3];
    float area = (by2 - by1) * (bx2 - bx1);
    float lvlf = logf(sqrtf(area)) * 1.4426950408889634f; // log2(sqrt(area))
    int level = (int)fminf(fmaxf(rintf(lvlf) + 4.0f, 0.0f), 3.0f);
    int W = 256 >> level;
    float scale = (float)W;
    P.W = W;
    P.bidx = bidxp[n];
    P.x1 = bx1 * scale;
    P.y1 = by1 * scale;
    P.bin_w = fmaxf((bx2 - bx1) * scale, 1.0f) * (1.0f / POOL);
    P.bin_h = fmaxf((by2 - by1) * scale, 1.0f) * (1.0f / POOL);

    float yA = P.y1 + P.bin_h * 0.25f, yB = P.y1 + P.bin_h * 6.75f;
    float xA = P.x1 + P.bin_w * 0.25f, xB = P.x1 + P.bin_w * 6.75f;
    int y0  = (int)floorf(fminf(fmaxf(yA, 0.f), (float)(W - 1)));
    int y1h = min((int)floorf(fminf(fmaxf(yB, 0.f), (float)(W - 1))) + 1, W - 1);
    int x0  = (int)floorf(fminf(fmaxf(xA, 0.f), (float)(W - 1)));
    x0 = min(x0, W - 2);                       // pair base can be one left of first xlo
    int x1p = min((int)floorf(fminf(fmaxf(xB, 0.f), (float)(W - 1))) + 1, W - 1);
    int ww = x1p - x0 + 1;
    int wh = y1h - y0 + 1;

    int x0a = x0 & ~3;
    int wwa = ((x1p - x0a + 1) + 3) & ~3;
    if ((wwa & 7) == 0 && (wwa + 4) * wh <= LDSF) wwa += 4;  // bank-stride rule
    int padded = wwa * wh;

    P.y0 = y0; P.x0 = x0; P.x0a = x0a; P.wwa = wwa; P.ww = ww;
    P.ngrp = (padded <= LDSF) ? (wwa >> 2) * wh : -1;
    int whc = min(wh, LDSF / ww);
    P.packed = ww * whc;
    return P;
}

// ---- per-lane sample table: BYTE offsets + premultiplied weights ----
// Computed in-kernel (~90 VALU, hides under staging). r13 measured that
// replacing this with a precomputed global table REGRESSES 86->109us:
// the dependent global-load chain + L2 pressure cost more than the VALU.
struct TabR {
    int o0[4], o1[4];
    float w00[4], w01[4], w10[4], w11[4];
};

__device__ __forceinline__ void make_tab_arrays(
    int lane, int W, int rs, int xb, int y0,
    float x1, float y1, float bin_w, float bin_h, TabR& tb)
{
    int cell = (lane < NCELL) ? lane : (NCELL - 1);
    int py = cell / POOL, px = cell % POOL;
#pragma unroll
    for (int s = 0; s < 4; ++s) {
        int sy = s >> 1, sx = s & 1;
        float y = y1 + bin_h * ((float)py + ((float)sy + 0.5f) * 0.5f);
        float x = x1 + bin_w * ((float)px + ((float)sx + 0.5f) * 0.5f);
        bool v = (y > -1.f) && (y < (float)W) && (x > -1.f) && (x < (float)W);
        float yc = fminf(fmaxf(y, 0.f), (float)(W - 1));
        float xc = fminf(fmaxf(x, 0.f), (float)(W - 1));
        int ylo = (int)floorf(yc), xlo = (int)floorf(xc);
        int yhi = min(ylo + 1, W - 1);
        float fy = yc - (float)ylo, fx = xc - (float)xlo;
        float vv = v ? 0.25f : 0.f;            // validity + 1/(SR*SR)
        int bxp = min(xlo, W - 2);             // keep float-pair in-row
        bool in = (xlo == bxp);
        float wx0 = in ? (1.f - fx) : 0.f;
        float wx1 = in ? fx : 1.f;
        float wr0 = (1.f - fy) * vv, wr1 = fy * vv;
        tb.o0[s] = ((ylo - y0) * rs + (bxp - xb)) * 4;   // byte offsets
        tb.o1[s] = ((yhi - y0) * rs + (bxp - xb)) * 4;
        tb.w00[s] = wr0 * wx0; tb.w01[s] = wr0 * wx1;
        tb.w10[s] = wr1 * wx0; tb.w11[s] = wr1 * wx1;
    }
}

// Plain-C consume: compiler merges pair reads to ds_read2_b32, emits
// fine-grained lgkmcnt, and can interleave ch0 FMAs with ch1 ds_reads
// (no asm fences / forced register moves).
__device__ __forceinline__ float consume(const float* cb, const TabR& tb)
{
    const char* b = (const char*)cb;
    float acc = 0.f;
#pragma unroll
    for (int s = 0; s < 4; ++s) {
        const float* q0 = (const float*)(b + tb.o0[s]);
        const float* q1 = (const float*)(b + tb.o1[s]);
        acc += tb.w00[s] * q0[0] + tb.w01[s] * q0[1]
             + tb.w10[s] * q1[0] + tb.w11[s] * q1[1];
    }
    return acc;
}

// ---- x4 path: 2-channel all-prefetch, one vmcnt rendezvous per task ----
// L0,L1 issued back-to-back return ~together, so one vmcnt(0) exposes no
// more latency than a split ledger. Stores regular cached (r9: WRITE at
// the compulsory floor via L2 write-back merging).
template <int NIT4>
__device__ __forceinline__ void box_x4(
    const float* fbase, float* outp, float* sm, int lane,
    int W, int HW, int wwa, int y0, int x0a, int ngrp, const TabR& tb)
{
    int g_off[NIT4];
    bool act[NIT4];
    int wwa4 = wwa >> 2;
#pragma unroll
    for (int k = 0; k < NIT4; ++k) {
        int idx = k * 64 + lane;
        act[k] = idx < ngrp;
        int ii = act[k] ? idx : 0;
        int r = ii / wwa4;
        int c = ii - r * wwa4;
        g_off[k] = (y0 + r) * W + x0a + c * 4;   // 16B-aligned (W%4==0, x0a%4==0)
    }
#pragma unroll
    for (int k = 0; k < NIT4; ++k)
        if (act[k]) stage16(fbase + g_off[k], sm + k * 256);
#pragma unroll
    for (int k = 0; k < NIT4; ++k)
        if (act[k]) stage16(fbase + (size_t)HW + g_off[k], sm + LDSF + k * 256);

    vwait0();
    float r0 = consume(sm, tb);
    if (lane < NCELL) outp[0] = r0;
    float r1 = consume(sm + LDSF, tb);
    if (lane < NCELL) outp[(size_t)NCELL] = r1;
}

// ---- scalar fallback for rare oversized padded windows ----
__device__ __forceinline__ void box_s(
    const float* fbase, float* outp, float* sm, int lane,
    int W, int HW, int ww, int y0, int x0, int packed, const TabR& tb)
{
    int g_off[NIT_S];
#pragma unroll
    for (int k = 0; k < NIT_S; ++k) {
        int idx = k * 64 + lane;
        idx = (idx < packed) ? idx : 0;
        int r = idx / ww;
        int c = idx - r * ww;
        g_off[k] = (y0 + r) * W + (x0 + c);
    }
#pragma unroll
    for (int k = 0; k < NIT_S; ++k) stage4(fbase + g_off[k], sm + k * 64);
#pragma unroll
    for (int k = 0; k < NIT_S; ++k) stage4(fbase + (size_t)HW + g_off[k], sm + LDSF + k * 64);

    vwait0();
    float r0 = consume(sm, tb);
    if (lane < NCELL) outp[0] = r0;
    float r1 = consume(sm + LDSF, tb);
    if (lane < NCELL) outp[(size_t)NCELL] = r1;
}

// ---- box ordering + per-box param precompute (sort kernel) ----
// Sort: counting sort by (level,batch,8x8 bucket) -> L2 locality (FETCH
// 171->56 MB measured). Output independent of order -> any permutation exact.
__device__ __forceinline__ int box_key(const float* boxes, const int* bidx, int n)
{
    float bx1 = boxes[4 * n + 0], by1 = boxes[4 * n + 1];
    float bx2 = boxes[4 * n + 2], by2 = boxes[4 * n + 3];
    float area = (by2 - by1) * (bx2 - bx1);
    float lvlf = logf(sqrtf(area)) * 1.4426950408889634f;
    int level = (int)fminf(fmaxf(rintf(lvlf) + 4.0f, 0.0f), 3.0f);
    int b = bidx[n] & 1;
    float cx = 0.5f * (bx1 + bx2), cy = 0.5f * (by1 + by2);
    int qx = min(7, max(0, (int)(cx * 8.0f)));
    int qy = min(7, max(0, (int)(cy * 8.0f)));
    return (((((level << 1) | b) << 3) | qy) << 3) | qx;   // < NBUCK
}

__global__ __launch_bounds__(NBUCK) void box_sort_kernel(
    const float* __restrict__ boxes, const int* __restrict__ bidx,
    int* __restrict__ perm, int* __restrict__ prm, int N)
{
    __shared__ int h0[NBUCK], h1[NBUCK];
    const int t = threadIdx.x;
    h0[t] = 0;
    __syncthreads();
    for (int n = t; n < N; n += NBUCK)
        atomicAdd(&h0[box_key(boxes, bidx, n)], 1);
    __syncthreads();
    int* src = h0; int* dst = h1;
    for (int off = 1; off < NBUCK; off <<= 1) {
        dst[t] = src[t] + ((t >= off) ? src[t - off] : 0);
        __syncthreads();
        int* tmp = src; src = dst; dst = tmp;
    }
    dst[t] = (t == 0) ? 0 : src[t - 1];   // exclusive base
    __syncthreads();
    for (int n = t; n < N; n += NBUCK) {
        int slot = atomicAdd(&dst[box_key(boxes, bidx, n)], 1);
        perm[slot] = n;
    }
    if (prm) {
        for (int n = t; n < N; n += NBUCK) {
            BoxP P = compute_boxp(boxes, bidx, n);
            int4* o = (int4*)(prm + (size_t)n * 16);
            o[0] = make_int4(P.W, P.bidx, P.y0, P.x0a);
            o[1] = make_int4(P.wwa, P.ngrp, P.x0, P.ww);
            o[2] = make_int4(P.packed, __float_as_int(P.x1),
                             __float_as_int(P.y1), __float_as_int(P.bin_w));
            o[3] = make_int4(__float_as_int(P.bin_h), 0, 0, 0);
        }
    }
}

// grid(32, N): linear id = c + 32*n -> XCD = c%8; channel slices pinned to L2.
__global__ __launch_bounds__(256, 8) void roi_align_fpn_kernel(
    const float* __restrict__ p2, const float* __restrict__ p3,
    const float* __restrict__ p4, const float* __restrict__ p5,
    const float* __restrict__ boxes, const int* __restrict__ bidx,
    const int* __restrict__ perm, const int* __restrict__ prm,
    float* __restrict__ out, int N)
{
    __shared__ float smem[4][CHPW][LDSF];   // 20480 B -> 8 blocks/CU (= caps)
    const int n = perm ? perm[blockIdx.y] : (int)blockIdx.y;
    const int t = threadIdx.x;
    const int wave = t >> 6;
    const int lane = t & 63;

    BoxP P;
    if (prm) {
        const int4* ip = (const int4*)(prm + (size_t)n * 16);
        int4 q0 = ip[0], q1 = ip[1], q2 = ip[2], q3 = ip[3];
        P.W = q0.x;  P.bidx = q0.y;  P.y0 = q0.z;  P.x0a = q0.w;
        P.wwa = q1.x; P.ngrp = q1.y; P.x0 = q1.z;  P.ww = q1.w;
        P.packed = q2.x;
        P.x1 = __int_as_float(q2.y); P.y1 = __int_as_float(q2.z);
        P.bin_w = __int_as_float(q2.w); P.bin_h = __int_as_float(q3.x);
    } else {
        P = compute_boxp(boxes, bidx, n);
    }

    TabR tb;
    {
        int rs = (P.ngrp >= 0) ? P.wwa : P.ww;
        int xb = (P.ngrp >= 0) ? P.x0a : P.x0;
        make_tab_arrays(lane, P.W, rs, xb, P.y0, P.x1, P.y1, P.bin_w, P.bin_h, tb);
    }

    const int W = P.W;
    const int HW = W * W;
    const float* feat = (W == 256) ? p2 : (W == 128) ? p3 : (W == 64) ? p4 : p5;
    feat += (size_t)P.bidx * NCH * HW;

    const int ch0 = blockIdx.x * CHPB + wave * CHPW;
    const float* fbase = feat + (size_t)ch0 * HW;
    float* sm = &smem[wave][0][0];
    int cell = (lane < NCELL) ? lane : (NCELL - 1);
    float* outp = out + (size_t)n * NCH * NCELL + (size_t)ch0 * NCELL + cell;

    if (P.ngrp >= 0) {
        int nit4 = (P.ngrp + 63) >> 6;         // in {1,2,3}
        if (nit4 == 1)      box_x4<1>(fbase, outp, sm, lane, W, HW, P.wwa, P.y0, P.x0a, P.ngrp, tb);
        else if (nit4 == 2) box_x4<2>(fbase, outp, sm, lane, W, HW, P.wwa, P.y0, P.x0a, P.ngrp, tb);
        else                box_x4<3>(fbase, outp, sm, lane, W, HW, P.wwa, P.y0, P.x0a, P.ngrp, tb);
    } else {
        box_s(fbase, outp, sm, lane, W, HW, P.ww, P.y0, P.x0, P.packed, tb);
    }
}

extern "C" void kernel_launch(void* const* d_in, const int* in_sizes, int n_in,
                              void* d_out, int out_size, void* d_ws, size_t ws_size,
                              hipStream_t stream) {
    const float* p2    = (const float*)d_in[0];
    const float* p3    = (const float*)d_in[1];
    const float* p4    = (const float*)d_in[2];
    const float* p5    = (const float*)d_in[3];
    const float* boxes = (const float*)d_in[4];
    const int*   bidx  = (const int*)d_in[5];
    float* out = (float*)d_out;
    int N = in_sizes[5];
    int* perm = nullptr;
    int* prm  = nullptr;
    size_t permB = ((size_t)N * 4 + 15) & ~(size_t)15;   // 16B-align params
    if (d_ws && ws_size >= permB + (size_t)N * 64) {
        perm = (int*)d_ws;
        prm  = (int*)((char*)d_ws + permB);
        box_sort_kernel<<<1, NBUCK, 0, stream>>>(boxes, bidx, perm, prm, N);
    } else if (d_ws && ws_size >= (size_t)N * 4) {
        perm = (int*)d_ws;
        box_sort_kernel<<<1, NBUCK, 0, stream>>>(boxes, bidx, perm, nullptr, N);
    }
    dim3 grid(CH_SPLIT, N);
    roi_align_fpn_kernel<<<grid, 256, 0, stream>>>(p2, p3, p4, p5, boxes, bidx, perm, prm, out, N);
}